// Round 3
// baseline (2482.961 us; speedup 1.0000x reference)
//
#include <hip/hip_runtime.h>
#include <hip/hip_bf16.h>

#define NB_  4096   // B_ = B*NW windows
#define NG_  49
#define NC_  128
#define NH_  4
#define DH_  32
#define NN_  50     // NG+1
#define NIMG 64
#define NT_  3136
#define SCALE_ 0.17677669529663687f

typedef unsigned short u16;

__device__ __forceinline__ float b2f(u16 u) {
    union { unsigned int i; float f; } v; v.i = ((unsigned int)u) << 16; return v.f;
}
__device__ __forceinline__ u16 f2b(float f) {
    union { float f; unsigned int i; } v; v.f = f;
    unsigned int x = v.i;
    return (u16)((x + 0x7fffu + ((x >> 16) & 1u)) >> 16);
}

struct WinShared {
    u16 xc[NN_][NC_];       // 12800 B (bf16-staged input)
    u16 q[NG_][NC_];        // 12544 B (scaled)
    u16 k[NN_][NC_];        // 12800 B
    u16 v[NN_][NC_];        // 12800 B
    float attn[NG_][NN_];   //  9800 B
};
struct GlobShared {
    float qa[NH_][DH_];
    float xavgS[NC_];
    float u[NH_][NC_];
    float cst[NH_];
    float smax[NH_];
    float ssum[NH_];
    float red[256];
    float wpart[2][NH_][NC_];
    float s[NT_][NH_];      // 50176 B
};
union SMem { WinShared w; GlobShared g; };

extern "C" __global__ __launch_bounds__(256, 2)
void wa2_kernel(const float* __restrict__ x, const float* __restrict__ xtotal,
                const float* __restrict__ xavg, const float* __restrict__ mask,
                const float* __restrict__ Wq, const float* __restrict__ bq,
                const float* __restrict__ Wkv, const float* __restrict__ bkv,
                const float* __restrict__ btab, const int* __restrict__ ridx,
                float* __restrict__ out)
{
    __shared__ SMem sm;
    const int t = threadIdx.x;
    const int blk = blockIdx.x;

    if (blk < NB_) {
        // ======================= window path =======================
        WinShared& S = sm.w;
        const int img  = blk >> 6;   // /64
        const int widx = blk & 63;

        // ---- load x_c = [x(49x128) ; xavg_row] into LDS as bf16 ----
        const float* xrow = x + (size_t)blk * (NG_ * NC_);
        u16* xcf = &S.xc[0][0];
        for (int i = t; i < NG_ * NC_; i += 256) xcf[i] = f2b(xrow[i]);
        if (t < NC_) xcf[NG_ * NC_ + t] = f2b(xavg[img * NC_ + t]);
        __syncthreads();

        // ---- qkv projection: rows strip per thread, one W column ----
        const int j  = t & 127;
        const int rg = t >> 7;       // 0 or 1
        const int r0 = rg * 25;      // rows [r0, r0+25)
        for (int jb = 0; jb < 3; ++jb) {
            const float* Wcol; int stride; float bias;
            if (jb == 0)      { Wcol = Wq  + j;        stride = NC_;     bias = bq[j]; }
            else if (jb == 1) { Wcol = Wkv + j;        stride = 2 * NC_; bias = bkv[j]; }
            else              { Wcol = Wkv + NC_ + j;  stride = 2 * NC_; bias = bkv[NC_ + j]; }
            float acc[25];
            #pragma unroll
            for (int r = 0; r < 25; ++r) acc[r] = 0.f;
            for (int c = 0; c < NC_; ++c) {
                float wv = Wcol[c * stride];
                #pragma unroll
                for (int r = 0; r < 25; ++r)
                    acc[r] += b2f(S.xc[r0 + r][c]) * wv;
            }
            if (jb == 0) {
                #pragma unroll
                for (int r = 0; r < 25; ++r) {
                    int row = r0 + r;
                    if (row < NG_) S.q[row][j] = f2b((acc[r] + bias) * SCALE_);
                }
            } else if (jb == 1) {
                #pragma unroll
                for (int r = 0; r < 25; ++r) S.k[r0 + r][j] = f2b(acc[r] + bias);
            } else {
                #pragma unroll
                for (int r = 0; r < 25; ++r) S.v[r0 + r][j] = f2b(acc[r] + bias);
            }
        }
        __syncthreads();

        // ---- per-head: scores + bias + mask, softmax, AV ----
        const float* mrow = mask + (size_t)widx * (NG_ * NN_);
        float* attnf = &S.attn[0][0];
        for (int h = 0; h < NH_; ++h) {
            const int jo = h * DH_;
            for (int e = t; e < NG_ * NN_; e += 256) {
                const int n = e / NN_, m = e - n * NN_;
                const u16* qr = &S.q[n][jo];
                const u16* kr = &S.k[m][jo];
                float acc = 0.f;
                #pragma unroll
                for (int jj = 0; jj < DH_; ++jj) acc += b2f(qr[jj]) * b2f(kr[jj]);
                acc += btab[ridx[e] * NH_ + h];
                acc += mrow[e];
                attnf[e] = acc;
            }
            __syncthreads();
            if (t < NG_) {
                float* row = &S.attn[t][0];
                float mx = row[0];
                for (int m = 1; m < NN_; ++m) mx = fmaxf(mx, row[m]);
                float ssum = 0.f;
                for (int m = 0; m < NN_; ++m) { float e = __expf(row[m] - mx); row[m] = e; ssum += e; }
                float inv = 1.f / ssum;
                for (int m = 0; m < NN_; ++m) row[m] *= inv;
            }
            __syncthreads();
            for (int e = t; e < NG_ * DH_; e += 256) {
                const int n = e >> 5, jj = e & 31;
                float acc = 0.f;
                for (int m = 0; m < NN_; ++m)
                    acc += S.attn[n][m] * b2f(S.v[m][jo + jj]);
                out[(size_t)blk * (NG_ * NC_) + n * NC_ + jo + jj] = acc;
            }
            __syncthreads();
        }
    } else {
        // ======================= global path =======================
        GlobShared& S = sm.g;
        const int img = blk - NB_;

        if (t < NC_) S.xavgS[t] = xavg[img * NC_ + t];
        __syncthreads();

        // q_avg (NOT scaled)
        if (t < NC_) {
            const int h = t >> 5, jj = t & 31;
            float acc = bq[h * DH_ + jj];
            for (int c = 0; c < NC_; ++c) acc += S.xavgS[c] * Wq[c * NC_ + h * DH_ + jj];
            S.qa[h][jj] = acc;
        }
        __syncthreads();

        // u[h][c] = sum_j Wk[c][h*32+j] * qa[h][j];  cst[h] = qa . bk
        if (t < NC_) {
            const int c = t;
            #pragma unroll
            for (int h = 0; h < NH_; ++h) {
                float acc = 0.f;
                const float* wr = Wkv + (size_t)c * (2 * NC_) + h * DH_;
                #pragma unroll
                for (int jj = 0; jj < DH_; ++jj) acc += wr[jj] * S.qa[h][jj];
                S.u[h][c] = acc;
            }
        } else if (t < NC_ + NH_) {
            const int h = t - NC_;
            float acc = 0.f;
            for (int jj = 0; jj < DH_; ++jj) acc += S.qa[h][jj] * bkv[h * DH_ + jj];
            S.cst[h] = acc;
        }
        __syncthreads();

        // scores over all 3136 patches, 4 heads at once
        float lmax0 = -1e30f, lmax1 = -1e30f, lmax2 = -1e30f, lmax3 = -1e30f;
        for (int m = t; m < NT_; m += 256) {
            const float* xr = xtotal + (size_t)(img * NT_ + m) * NC_;
            float a0 = S.cst[0], a1 = S.cst[1], a2 = S.cst[2], a3 = S.cst[3];
            for (int c = 0; c < NC_; ++c) {
                float xv = xr[c];
                a0 += xv * S.u[0][c];
                a1 += xv * S.u[1][c];
                a2 += xv * S.u[2][c];
                a3 += xv * S.u[3][c];
            }
            S.s[m][0] = a0; S.s[m][1] = a1; S.s[m][2] = a2; S.s[m][3] = a3;
            lmax0 = fmaxf(lmax0, a0); lmax1 = fmaxf(lmax1, a1);
            lmax2 = fmaxf(lmax2, a2); lmax3 = fmaxf(lmax3, a3);
        }
        float lm[NH_] = {lmax0, lmax1, lmax2, lmax3};
        for (int h = 0; h < NH_; ++h) {
            __syncthreads();
            S.red[t] = lm[h];
            __syncthreads();
            for (int off = 128; off > 0; off >>= 1) {
                if (t < off) S.red[t] = fmaxf(S.red[t], S.red[t + off]);
                __syncthreads();
            }
            if (t == 0) S.smax[h] = S.red[0];
        }
        __syncthreads();

        float ls[NH_] = {0.f, 0.f, 0.f, 0.f};
        for (int m = t; m < NT_; m += 256) {
            #pragma unroll
            for (int h = 0; h < NH_; ++h) {
                float e = __expf(S.s[m][h] - S.smax[h]);
                S.s[m][h] = e;
                ls[h] += e;
            }
        }
        for (int h = 0; h < NH_; ++h) {
            __syncthreads();
            S.red[t] = ls[h];
            __syncthreads();
            for (int off = 128; off > 0; off >>= 1) {
                if (t < off) S.red[t] += S.red[t + off];
                __syncthreads();
            }
            if (t == 0) S.ssum[h] = S.red[0];
        }
        __syncthreads();

        // w[h][c] = sum_m e_m * xtotal[m][c]  (split key range in halves)
        {
            const int c = t & 127, half = t >> 7;
            float a0 = 0.f, a1 = 0.f, a2 = 0.f, a3 = 0.f;
            const int m0 = half * (NT_ / 2), m1 = m0 + NT_ / 2;
            for (int m = m0; m < m1; ++m) {
                float xv = xtotal[(size_t)(img * NT_ + m) * NC_ + c];
                a0 += S.s[m][0] * xv; a1 += S.s[m][1] * xv;
                a2 += S.s[m][2] * xv; a3 += S.s[m][3] * xv;
            }
            S.wpart[half][0][c] = a0; S.wpart[half][1][c] = a1;
            S.wpart[half][2][c] = a2; S.wpart[half][3][c] = a3;
        }
        __syncthreads();

        // out = (w/ssum) @ Wv + bv
        if (t < NC_) {
            const int h = t >> 5, jj = t & 31;
            const float winv = 1.f / S.ssum[h];
            float acc = bkv[NC_ + h * DH_ + jj];
            for (int c = 0; c < NC_; ++c) {
                float wv = (S.wpart[0][h][c] + S.wpart[1][h][c]) * winv;
                acc += wv * Wkv[(size_t)c * (2 * NC_) + NC_ + h * DH_ + jj];
            }
            out[(size_t)NB_ * (NG_ * NC_) + img * NC_ + t] = acc;
        }
    }
}

extern "C" void kernel_launch(void* const* d_in, const int* in_sizes, int n_in,
                              void* d_out, int out_size, void* d_ws, size_t ws_size,
                              hipStream_t stream) {
    const float* x      = (const float*)d_in[0];
    const float* xtotal = (const float*)d_in[1];
    const float* xavg   = (const float*)d_in[2];
    const float* mask   = (const float*)d_in[3];
    const float* Wq     = (const float*)d_in[4];
    const float* bq     = (const float*)d_in[5];
    const float* Wkv    = (const float*)d_in[6];
    const float* bkv    = (const float*)d_in[7];
    const float* btab   = (const float*)d_in[8];
    const int*   ridx   = (const int*)d_in[9];
    float* outp = (float*)d_out;
    (void)in_sizes; (void)n_in; (void)out_size; (void)d_ws; (void)ws_size;

    wa2_kernel<<<NB_ + NIMG, 256, 0, stream>>>(x, xtotal, xavg, mask, Wq, bq,
                                               Wkv, bkv, btab, ridx, outp);
}